// Round 2
// baseline (204.053 us; speedup 1.0000x reference)
//
#include <hip/hip_runtime.h>
#include <hip/hip_cooperative_groups.h>
#include <math.h>

namespace cg = cooperative_groups;

#define NC   19
#define HH   256
#define WW   256
#define NB   4
#define HW   (HH * WW)       // 65536
#define TS   32
#define HALO 10
#define FW   (TS + 2 * HALO) // 52
#define CAP2 121.0f          // (RAD+1)^2 — any value >100 is masked identically

// ---------------------------------------------------------------------------
// Single cooperative kernel. 256 blocks (8x8 tiles x 4 images) x 512 threads
// = 8 waves/CU, fully co-resident (26 KB LDS, moderate VGPR).
//
// Phase 1: each block computes ent/kl/fg for its own 32x32 tile.
//   - float2 loads (2 adjacent px/thread), same shift-free softmax moments:
//       St = sum e^{t/4}, T1 = sum e^{t/4} t, T2 = sum e^{t/4} s, Ss = sum e^{s/4}
//       ent = ln St - T1/(4 St);  kl = ln Ss - T2/(4 St) - ent
//   - ent/kl stay in LDS (no HBM round trip). fg byte map + per-block entropy
//     max go to global (needed by neighbor halos / image-max reduction).
// grid.sync()
// Phase 2: windowed EDT (exact for the result: any entry at distance > 10
//   gives d2 >= 121 > 100 -> mask = 0 either way) + epilogue from LDS;
//   one plain 16B partial store per block (zero contention).
// grid.sync()
// Phase 3: block 0 reduces the 256 partial pairs, emits scalar.
// All per-pixel math and summation orders identical to the verified 3-kernel
// version (fmax regrouping is exact) -> absmax 0 expected.
// ---------------------------------------------------------------------------
__global__ __launch_bounds__(512) void k_fused(
    const float* __restrict__ student, const float* __restrict__ teacher,
    unsigned char* __restrict__ fg, float* __restrict__ bmax,
    double* __restrict__ part, float* __restrict__ out)
{
    __shared__ float  fgt[FW][FW];
    __shared__ float  ent_s[TS][TS];
    __shared__ float  kl_s[TS][TS];
    __shared__ float  vm[TS][FW];
    __shared__ float  redf[8];
    __shared__ double snum[8], sden[8];

    const int b   = blockIdx.z;
    const int ti0 = blockIdx.y * TS;
    const int tj0 = blockIdx.x * TS;
    const int tid = threadIdx.x;
    const int wave = tid >> 6, lane = tid & 63;
    unsigned char* fgb = fg + (size_t)b * HW;

    // ---------------- Phase 1: per-pixel channel pass for own tile --------
    {
        const int i  = tid >> 4;          // 0..31 tile row
        const int j0 = (tid & 15) << 1;   // 0,2,...,30 (pixel pair)
        const size_t base = (size_t)b * NC * HW + (size_t)(ti0 + i) * WW + (tj0 + j0);
        const float2* tp = (const float2*)(teacher + base);
        const float2* sp = (const float2*)(student + base);

        float St0 = 0.f, St1 = 0.f, T10 = 0.f, T11 = 0.f;
        float T20 = 0.f, T21 = 0.f, Ss0 = 0.f, Ss1 = 0.f;
        float tm0 = -INFINITY, tm1 = -INFINITY;
        int ax0 = 0, ax1 = 0;
#pragma unroll
        for (int c = 0; c < NC; ++c) {
            float2 tv = tp[(size_t)c * (HW / 2)];
            float2 sv = sp[(size_t)c * (HW / 2)];
            if (tv.x > tm0) { tm0 = tv.x; ax0 = c; }     // first-max argmax
            float e0 = __expf(tv.x * 0.25f);
            St0 += e0; T10 += e0 * tv.x; T20 += e0 * sv.x;
            Ss0 += __expf(sv.x * 0.25f);
            if (tv.y > tm1) { tm1 = tv.y; ax1 = c; }
            float e1 = __expf(tv.y * 0.25f);
            St1 += e1; T11 += e1 * tv.y; T21 += e1 * sv.y;
            Ss1 += __expf(sv.y * 0.25f);
        }
        float r0 = 1.0f / St0, r1 = 1.0f / St1;
        float e0 = __logf(St0) - 0.25f * T10 * r0;
        float e1 = __logf(St1) - 0.25f * T11 * r1;
        float k0 = __logf(Ss0) - 0.25f * T20 * r0 - e0;
        float k1 = __logf(Ss1) - 0.25f * T21 * r1 - e1;

        ent_s[i][j0]     = e0;  ent_s[i][j0 + 1] = e1;
        kl_s[i][j0]      = k0;  kl_s[i][j0 + 1]  = k1;
        unsigned char f0 = (ax0 != 0) ? 1 : 0;
        unsigned char f1 = (ax1 != 0) ? 1 : 0;
        fgt[HALO + i][HALO + j0]     = (float)f0;
        fgt[HALO + i][HALO + j0 + 1] = (float)f1;
        uchar2 fpair; fpair.x = f0; fpair.y = f1;
        *(uchar2*)(fgb + (size_t)(ti0 + i) * WW + (tj0 + j0)) = fpair;  // even addr

        // per-block (tile) entropy max -> bmax slot
        float em = fmaxf(e0, e1);
#pragma unroll
        for (int o = 32; o >= 1; o >>= 1) em = fmaxf(em, __shfl_down(em, o, 64));
        if (lane == 0) redf[wave] = em;
        __syncthreads();
        if (tid == 0) {
            float mm = redf[0];
#pragma unroll
            for (int w = 1; w < 8; ++w) mm = fmaxf(mm, redf[w]);
            bmax[(b << 6) + (blockIdx.y << 3) + blockIdx.x] = mm;
        }
    }
    __threadfence();
    cg::this_grid().sync();

    // ---------------- Phase 2: windowed EDT + epilogue --------------------
    // per-image entropy max from the image's 64 tile maxima (exact fmax)
    float m = bmax[(b << 6) + lane];
#pragma unroll
    for (int o = 32; o >= 1; o >>= 1) m = fmaxf(m, __shfl_xor(m, o, 64));
    const float em = m;

    // halo ring from global (interior already in LDS from phase 1);
    // out-of-image -> 0 == border_value=0
    for (int l = tid; l < FW * FW; l += 512) {
        int li = l / FW, lj = l - li * FW;
        if (li >= HALO && li < HALO + TS && lj >= HALO && lj < HALO + TS) continue;
        int gi = ti0 - HALO + li, gj = tj0 - HALO + lj;
        float v = 0.f;
        if (gi >= 0 && gi < HH && gj >= 0 && gj < WW) v = (float)fgb[gi * WW + gj];
        fgt[li][lj] = v;
    }
    __syncthreads();

    // vertical windowed min (branchless); lanes hit consecutive banks
    for (int l = tid; l < TS * FW; l += 512) {
        int i = l / FW, jj = l - i * FW;
        float mn = CAP2;
#pragma unroll
        for (int di = -HALO; di <= HALO; ++di) {
            float fv = fgt[HALO + i + di][jj];
            mn = fminf(mn, (float)(di * di) + (1.0f - fv) * 1000.0f);
        }
        vm[i][jj] = mn;
    }
    __syncthreads();

    double num = 0.0, den = 0.0;
#pragma unroll
    for (int k = 0; k < 2; ++k) {                    // 2 pixels/thread
        int p = tid + k * 512;
        int i = p >> 5, j = p & (TS - 1);
        float d2 = CAP2;
#pragma unroll
        for (int dj = -HALO; dj <= HALO; ++dj)
            d2 = fminf(d2, (float)(dj * dj) + vm[i][j + HALO + dj]);
        float mask  = (d2 <= 100.0f) ? 1.0f : 0.0f;
        float wdist = __expf(-d2 * 0.02f) * mask;    // exp(-d2/(2*5^2))

        float f  = fgt[HALO + i][HALO + j];
        float up = fgt[HALO + i - 1][HALO + j];
        float dn = fgt[HALO + i + 1][HALO + j];
        float lf = fgt[HALO + i][HALO + j - 1];
        float rt = fgt[HALO + i][HALO + j + 1];
        float mn4 = fminf(fminf(up, dn), fminf(lf, rt));
        float boundary = (f != 0.f && mn4 == 0.f) ? 1.0f : 0.0f;

        float w = wdist * (1.0f + boundary) * mask;
        float conf = 0.1f + 0.9f * (1.0f - ent_s[i][j] / (em + 1e-8f));
        float tw = w * conf;
        num += (double)(tw * kl_s[i][j]);
        den += (double)tw;
    }

#pragma unroll
    for (int o = 32; o >= 1; o >>= 1) {
        num += __shfl_down(num, o, 64);
        den += __shfl_down(den, o, 64);
    }
    if (lane == 0) { snum[wave] = num; sden[wave] = den; }
    __syncthreads();
    if (tid == 0) {
        double n = 0.0, d = 0.0;
#pragma unroll
        for (int w = 0; w < 8; ++w) { n += snum[w]; d += sden[w]; }
        int bid = (blockIdx.z << 6) + (blockIdx.y << 3) + blockIdx.x;  // 0..255
        part[bid * 2 + 0] = n;
        part[bid * 2 + 1] = d;
    }
    __threadfence();
    cg::this_grid().sync();

    // ---------------- Phase 3: block 0 reduces 256 partials ---------------
    if (blockIdx.x == 0 && blockIdx.y == 0 && blockIdx.z == 0) {
        double n2 = 0.0, d2 = 0.0;
        if (tid < 256) { n2 = part[tid * 2 + 0]; d2 = part[tid * 2 + 1]; }
#pragma unroll
        for (int o = 32; o >= 1; o >>= 1) {
            n2 += __shfl_down(n2, o, 64);
            d2 += __shfl_down(d2, o, 64);
        }
        if (lane == 0) { snum[wave] = n2; sden[wave] = d2; }
        __syncthreads();
        if (tid == 0) {
            double n = snum[0] + snum[1] + snum[2] + snum[3];
            double d = sden[0] + sden[1] + sden[2] + sden[3];
            out[0] = (float)(16.0 * n / (d + 1e-8));
        }
    }
}

extern "C" void kernel_launch(void* const* d_in, const int* in_sizes, int n_in,
                              void* d_out, int out_size, void* d_ws, size_t ws_size,
                              hipStream_t stream)
{
    const float* student = (const float*)d_in[0];
    const float* teacher = (const float*)d_in[1];
    float* out = (float*)d_out;

    char* ws = (char*)d_ws;
    double*        part = (double*)(ws + 0);      // 512 doubles
    float*         bmax = (float*)(ws + 8192);    // 256 floats
    unsigned char* fg   = (unsigned char*)(ws + 16384);  // NPIX bytes

    dim3 grid(WW / TS, HH / TS, NB);   // (8, 8, 4) = 256 blocks
    dim3 block(512);
    void* args[] = { (void*)&student, (void*)&teacher, (void*)&fg,
                     (void*)&bmax, (void*)&part, (void*)&out };
    hipLaunchCooperativeKernel((const void*)k_fused, grid, block, args, 0, stream);
}

// Round 3
// 85.591 us; speedup vs baseline: 2.3840x; 2.3840x over previous
//
#include <hip/hip_runtime.h>
#include <math.h>

#define NC   19
#define HH   256
#define WW   256
#define NB   4
#define HW   (HH * WW)       // 65536
#define NPIX (NB * HW)       // 262144
#define NP2  (NPIX / 2)      // 131072 pixel-pairs
#define CH2  (HW / 2)        // 32768 float2 per channel-image plane
#define CAP2 121.0f          // (RAD+1)^2 — any value >100 is masked identically

// ---------------------------------------------------------------------------
// Kernel 1: per-pixel channel pass, float2 (2 px/thread), 512 blocks x 256
// threads = 2 blocks/CU, 8 waves/CU (round-1 float4 version was 1 block/CU,
// 4 waves/CU — latency-poor). Shift-free softmax moments (verified exact):
//   St = sum e^{t/4}, T1 = sum e^{t/4} t, T2 = sum e^{t/4} s, Ss = sum e^{s/4}
//   ent = ln St - T1/(4 St);  kl = ln Ss - T2/(4 St) - ent
// ent/kl packed as float2 -> one 16B store per thread, one 8B load per pixel
// in k_tile.
// ---------------------------------------------------------------------------
__global__ __launch_bounds__(256) void k_pixel(
    const float2* __restrict__ student, const float2* __restrict__ teacher,
    float4* __restrict__ ekl, uchar2* __restrict__ fg, float* __restrict__ bmax)
{
    const int p2 = blockIdx.x * 256 + threadIdx.x;   // 0..131071
    const int b  = p2 >> 15;                          // 32768 pairs per image
    const int r2 = p2 & (CH2 - 1);
    const float2* tp = teacher + (size_t)b * NC * CH2 + r2;
    const float2* sp = student + (size_t)b * NC * CH2 + r2;

    float St0 = 0.f, St1 = 0.f, T10 = 0.f, T11 = 0.f;
    float T20 = 0.f, T21 = 0.f, Ss0 = 0.f, Ss1 = 0.f;
    float tm0 = -INFINITY, tm1 = -INFINITY;
    int ax0 = 0, ax1 = 0;
#pragma unroll
    for (int c = 0; c < NC; ++c) {
        float2 tv = tp[(size_t)c * CH2];
        float2 sv = sp[(size_t)c * CH2];
        if (tv.x > tm0) { tm0 = tv.x; ax0 = c; }     // first-max argmax
        float e0 = __expf(tv.x * 0.25f);
        St0 += e0; T10 += e0 * tv.x; T20 += e0 * sv.x;
        Ss0 += __expf(sv.x * 0.25f);
        if (tv.y > tm1) { tm1 = tv.y; ax1 = c; }
        float e1 = __expf(tv.y * 0.25f);
        St1 += e1; T11 += e1 * tv.y; T21 += e1 * sv.y;
        Ss1 += __expf(sv.y * 0.25f);
    }
    float r0 = 1.0f / St0, r1 = 1.0f / St1;
    float e0 = __logf(St0) - 0.25f * T10 * r0;
    float e1 = __logf(St1) - 0.25f * T11 * r1;
    float k0 = __logf(Ss0) - 0.25f * T20 * r0 - e0;
    float k1 = __logf(Ss1) - 0.25f * T21 * r1 - e1;

    float4 v; v.x = e0; v.y = k0; v.z = e1; v.w = k1;
    ekl[p2] = v;                                      // {ent,kl} x 2 pixels
    uchar2 f; f.x = (ax0 != 0) ? 1 : 0; f.y = (ax1 != 0) ? 1 : 0;
    fg[p2] = f;

    // per-block (512-pixel) entropy max; blocks never straddle images
    float em = fmaxf(e0, e1);
#pragma unroll
    for (int o = 32; o >= 1; o >>= 1) em = fmaxf(em, __shfl_down(em, o, 64));
    __shared__ float red[4];
    int wave = threadIdx.x >> 6, lane = threadIdx.x & 63;
    if (lane == 0) red[wave] = em;
    __syncthreads();
    if (threadIdx.x == 0)
        bmax[blockIdx.x] = fmaxf(fmaxf(red[0], red[1]), fmaxf(red[2], red[3]));
}

// ---------------------------------------------------------------------------
// Kernel 2: 32x32-tile windowed EDT + epilogue, 512 threads/block (verified
// round-1 structure). Windowed min is exact for the result: any entry at
// distance > 10 gives d2 >= 121 > 100 -> mask = 0 either way. Partial sums
// plain-stored to private slots (zero contention); k_final reduces.
// ---------------------------------------------------------------------------
#define TS   32
#define HALO 10
#define FW   (TS + 2 * HALO)  // 52

__global__ __launch_bounds__(512) void k_tile(
    const unsigned char* __restrict__ fg, const float2* __restrict__ ekl,
    const float* __restrict__ bmax, double* __restrict__ part)
{
    __shared__ float  fgt[FW][FW];
    __shared__ float  vm[TS][FW];
    __shared__ double snum[8], sden[8];

    const int b   = blockIdx.z;
    const int ti0 = blockIdx.y * TS;
    const int tj0 = blockIdx.x * TS;
    const int tid = threadIdx.x;
    const int wave = tid >> 6, lane = tid & 63;
    const unsigned char* fgb = fg + (size_t)b * HW;

    // per-image entropy max from this image's 128 per-block maxima.
    // Every wave butterfly-reduces its own copy — no smem, no extra sync.
    float m = fmaxf(bmax[(b << 7) + lane], bmax[(b << 7) + 64 + lane]);
#pragma unroll
    for (int o = 32; o >= 1; o >>= 1) m = fmaxf(m, __shfl_xor(m, o, 64));
    const float em = m;

    // fg tile + halo as float (out-of-image -> 0 == border_value=0)
    for (int l = tid; l < FW * FW; l += 512) {
        int li = l / FW, lj = l - li * FW;
        int gi = ti0 - HALO + li, gj = tj0 - HALO + lj;
        float v = 0.f;
        if (gi >= 0 && gi < HH && gj >= 0 && gj < WW) v = (float)fgb[gi * WW + gj];
        fgt[li][lj] = v;
    }
    __syncthreads();

    // vertical windowed min (branchless); lanes hit consecutive banks
    for (int l = tid; l < TS * FW; l += 512) {
        int i = l / FW, jj = l - i * FW;
        float mn = CAP2;
#pragma unroll
        for (int di = -HALO; di <= HALO; ++di) {
            float fv = fgt[HALO + i + di][jj];
            mn = fminf(mn, (float)(di * di) + (1.0f - fv) * 1000.0f);
        }
        vm[i][jj] = mn;
    }
    __syncthreads();

    double num = 0.0, den = 0.0;
#pragma unroll
    for (int k = 0; k < (TS * TS) / 512; ++k) {      // 2 pixels/thread
        int p = tid + k * 512;
        int i = p >> 5, j = p & (TS - 1);
        float d2 = CAP2;
#pragma unroll
        for (int dj = -HALO; dj <= HALO; ++dj)
            d2 = fminf(d2, (float)(dj * dj) + vm[i][j + HALO + dj]);
        float mask  = (d2 <= 100.0f) ? 1.0f : 0.0f;
        float wdist = __expf(-d2 * 0.02f) * mask;    // exp(-d2/(2*5^2))

        float f  = fgt[HALO + i][HALO + j];
        float up = fgt[HALO + i - 1][HALO + j];
        float dn = fgt[HALO + i + 1][HALO + j];
        float lf = fgt[HALO + i][HALO + j - 1];
        float rt = fgt[HALO + i][HALO + j + 1];
        float mn4 = fminf(fminf(up, dn), fminf(lf, rt));
        float boundary = (f != 0.f && mn4 == 0.f) ? 1.0f : 0.0f;

        float w = wdist * (1.0f + boundary) * mask;
        size_t gidx = (size_t)b * HW + (size_t)(ti0 + i) * WW + (tj0 + j);
        float2 ek = ekl[gidx];                        // {ent, kl}
        float conf = 0.1f + 0.9f * (1.0f - ek.x / (em + 1e-8f));
        float tw = w * conf;
        num += (double)(tw * ek.y);
        den += (double)tw;
    }

    // block reduce -> one plain 16B store to this block's private slot
#pragma unroll
    for (int o = 32; o >= 1; o >>= 1) {
        num += __shfl_down(num, o, 64);
        den += __shfl_down(den, o, 64);
    }
    if (lane == 0) { snum[wave] = num; sden[wave] = den; }
    __syncthreads();
    if (tid == 0) {
        double n = 0.0, d = 0.0;
#pragma unroll
        for (int wv = 0; wv < 8; ++wv) { n += snum[wv]; d += sden[wv]; }
        int bid = (blockIdx.z << 6) + (blockIdx.y << 3) + blockIdx.x;  // 0..255
        part[bid * 2 + 0] = n;
        part[bid * 2 + 1] = d;
    }
}

// ---------------------------------------------------------------------------
// Kernel 3: reduce 256 (num,den) partials, emit scalar. No atomics anywhere.
// Cross-kernel visibility of the plain stores is guaranteed by stream order.
// ---------------------------------------------------------------------------
__global__ __launch_bounds__(256) void k_final(
    const double* __restrict__ part, float* __restrict__ out)
{
    const int tid = threadIdx.x;
    double num = part[tid * 2 + 0];
    double den = part[tid * 2 + 1];
#pragma unroll
    for (int o = 32; o >= 1; o >>= 1) {
        num += __shfl_down(num, o, 64);
        den += __shfl_down(den, o, 64);
    }
    __shared__ double snum[4], sden[4];
    int wave = tid >> 6, lane = tid & 63;
    if (lane == 0) { snum[wave] = num; sden[wave] = den; }
    __syncthreads();
    if (tid == 0) {
        num = snum[0] + snum[1] + snum[2] + snum[3];
        den = sden[0] + sden[1] + sden[2] + sden[3];
        out[0] = (float)(16.0 * num / (den + 1e-8));
    }
}

extern "C" void kernel_launch(void* const* d_in, const int* in_sizes, int n_in,
                              void* d_out, int out_size, void* d_ws, size_t ws_size,
                              hipStream_t stream)
{
    const float2* student = (const float2*)d_in[0];
    const float2* teacher = (const float2*)d_in[1];
    float* out = (float*)d_out;

    char* ws = (char*)d_ws;
    double*        part = (double*)(ws + 0);              // 512 doubles
    float*         bmax = (float*)(ws + 8192);            // 512 floats
    float4*        ekl  = (float4*)(ws + 16384);          // NPIX float2 pairs
    unsigned char* fg   = (unsigned char*)(ws + 16384 + (size_t)NPIX * 8);

    k_pixel<<<NP2 / 256, 256, 0, stream>>>(student, teacher, ekl, (uchar2*)fg, bmax);
    dim3 g2(WW / TS, HH / TS, NB);
    k_tile<<<g2, 512, 0, stream>>>(fg, (const float2*)ekl, bmax, part);
    k_final<<<1, 256, 0, stream>>>(part, out);
}